// Round 8
// baseline (169.517 us; speedup 1.0000x reference)
//
#include <hip/hip_runtime.h>
#include <cstdint>

namespace {
constexpr int T = 1024;
constexpr int B = 8;
constexpr int D = 512;
constexpr int W = 32;
constexpr int M = T * B; // 8192 rows (t*B+b)
}

using half8  = __attribute__((ext_vector_type(8))) _Float16;
using f32x16 = __attribute__((ext_vector_type(16))) float;

__device__ __forceinline__ void gload16(const void* g, void* l) {
    __builtin_amdgcn_global_load_lds(
        (const __attribute__((address_space(1))) void*)g,
        (__attribute__((address_space(3))) void*)l, 16, 0, 0);
}

__device__ __forceinline__ float fast_tanh(float x) {
    float e = __expf(2.f * x);
    return 1.f - 2.f / (e + 1.f);
}

// Grid-wide flag barrier: release-add then acquire-spin on tid 0.
__device__ __forceinline__ void gbar(unsigned* cnt, unsigned target) {
    __syncthreads();
    __threadfence(); // flush this block's writes to device coherence point
    if (threadIdx.x == 0) {
        __hip_atomic_fetch_add(cnt, 1u, __ATOMIC_ACQ_REL, __HIP_MEMORY_SCOPE_AGENT);
        while (__hip_atomic_load(cnt, __ATOMIC_ACQUIRE, __HIP_MEMORY_SCOPE_AGENT) < target)
            __builtin_amdgcn_s_sleep(2);
    }
    __syncthreads();
}

// ---------- phase A: X fp32 -> Ah fp16 (grid-stride); W -> Bt^T on blocks 0..63
__device__ __forceinline__ void phase_prep(int bid, int tid, int nblk,
                                           const float* __restrict__ X,
                                           const float* __restrict__ Wm,
                                           _Float16* __restrict__ Ah,
                                           _Float16* __restrict__ Bt,
                                           char* lds)
{
    const int nthr = nblk * 256;
    const float4* X4 = reinterpret_cast<const float4*>(X);
    for (int c = bid * 256 + tid; c < M * D / 8; c += nthr) {
        const float4 v0 = X4[(size_t)c * 2];
        const float4 v1 = X4[(size_t)c * 2 + 1];
        half8 h;
        h[0] = (_Float16)v0.x; h[1] = (_Float16)v0.y; h[2] = (_Float16)v0.z; h[3] = (_Float16)v0.w;
        h[4] = (_Float16)v1.x; h[5] = (_Float16)v1.y; h[6] = (_Float16)v1.z; h[7] = (_Float16)v1.w;
        *reinterpret_cast<half8*>(Ah + (size_t)c * 8) = h;
    }

    if (bid < 64) {
        float (*tile)[65] = reinterpret_cast<float (*)[65]>(lds);
        const int bd = bid & 7;
        const int be = bid >> 3;
        const int r  = tid >> 2;
        const int c0 = (tid & 3) * 16;
        const float* src = Wm + (size_t)(be * 64 + r) * 512 + bd * 64 + c0;
#pragma unroll
        for (int j = 0; j < 16; j += 4) {
            const float4 v = *reinterpret_cast<const float4*>(src + j);
            tile[r][c0 + j]     = v.x;
            tile[r][c0 + j + 1] = v.y;
            tile[r][c0 + j + 2] = v.z;
            tile[r][c0 + j + 3] = v.w;
        }
        __syncthreads();
        const int dd = tid >> 2;
        const int e0 = (tid & 3) * 16;
        half8 h0, h1;
#pragma unroll
        for (int j = 0; j < 8; ++j)  h0[j] = (_Float16)tile[e0 + j][dd];
#pragma unroll
        for (int j = 0; j < 8; ++j)  h1[j] = (_Float16)tile[e0 + 8 + j][dd];
        _Float16* dst = Bt + (size_t)(bd * 64 + dd) * 512 + be * 64 + e0;
        *reinterpret_cast<half8*>(dst)     = h0;
        *reinterpret_cast<half8*>(dst + 8) = h1;
    }
}

// ---------- phase B: GEMM + tanh + proj-dot -> spart[8][M] (round-7 verbatim,
// tile 64x128, 512 tiles; LDS 2 bufs x (A 8K | B 16K) = 48 KB)
__device__ __forceinline__ void phase_gemm(int bid, int tid,
                                           const _Float16* __restrict__ Ah,
                                           const _Float16* __restrict__ Bt,
                                           const float* __restrict__ proj,
                                           float* __restrict__ spart,
                                           char* lds)
{
    const int lane = tid & 63;
    const int wv   = tid >> 6;
    const int wm   = wv >> 1;
    const int wn   = wv & 1;
    const int hi   = lane >> 5;
    const int l31  = lane & 31;
    const int l7   = lane & 7;

    const int wgid = (bid & 7) * 64 + (bid >> 3); // XCD-aware swizzle
    const int mb   = wgid >> 2;
    const int nb   = wgid & 3;
    const int m0   = mb * 64;
    const int n0   = nb * 128;

    const int wbase = __builtin_amdgcn_readfirstlane(tid & ~63);

    f32x16 acc0 = {}, acc1 = {};

    auto stage = [&](int bufi, int kt) {
        char* abase = lds + bufi * 24576;
        char* bbase = abase + 8192;
        const int kbase = kt * 64;
#pragma unroll
        for (int i = 0; i < 2; ++i) {
            const int c   = i * 256 + tid;
            const int row = c >> 3;
            const int ch  = c & 7;
            const int koff = kbase + ((ch ^ (row & 7)) << 3);
            gload16(Ah + (size_t)(m0 + row) * 512 + koff,
                    abase + (size_t)(i * 256 + wbase) * 16);
        }
#pragma unroll
        for (int i = 0; i < 4; ++i) {
            const int c   = i * 256 + tid;
            const int row = c >> 3;
            const int ch  = c & 7;
            const int koff = kbase + ((ch ^ (row & 7)) << 3);
            gload16(Bt + (size_t)(n0 + row) * 512 + koff,
                    bbase + (size_t)(i * 256 + wbase) * 16);
        }
    };

    stage(0, 0);
    asm volatile("s_waitcnt vmcnt(0)" ::: "memory");
    __syncthreads();

    int cur = 0;
    const int rowA  = wm * 32 + l31;
    const int colB0 = wn * 64 + l31;
    const int colB1 = colB0 + 32;

    for (int kt = 0; kt < 8; ++kt) {
        if (kt < 7) stage(cur ^ 1, kt + 1);

        const char* Ab = lds + cur * 24576;
        const char* Bb = Ab + 8192;

        half8 af[4], bf0[4], bf1[4];
#pragma unroll
        for (int s = 0; s < 4; ++s) {
            const int ch = ((2 * s + hi) ^ l7) << 4;
            af[s]  = *reinterpret_cast<const half8*>(Ab + rowA  * 128 + ch);
            bf0[s] = *reinterpret_cast<const half8*>(Bb + colB0 * 128 + ch);
            bf1[s] = *reinterpret_cast<const half8*>(Bb + colB1 * 128 + ch);
        }
        __builtin_amdgcn_s_setprio(1);
#pragma unroll
        for (int s = 0; s < 4; ++s) {
            acc0 = __builtin_amdgcn_mfma_f32_32x32x16_f16(af[s], bf0[s], acc0, 0, 0, 0);
            acc1 = __builtin_amdgcn_mfma_f32_32x32x16_f16(af[s], bf1[s], acc1, 0, 0, 0);
        }
        __builtin_amdgcn_s_setprio(0);

        if (kt < 7) asm volatile("s_waitcnt vmcnt(0)" ::: "memory");
        __syncthreads();
        cur ^= 1;
    }

    const float pj0 = proj[n0 + wn * 64 + l31];
    const float pj1 = proj[n0 + wn * 64 + 32 + l31];
    float* sp = spart + (size_t)(nb * 2 + wn) * M;

#pragma unroll
    for (int reg = 0; reg < 16; ++reg) {
        float v0 = fast_tanh(acc0[reg]) * pj0 + fast_tanh(acc1[reg]) * pj1;
#pragma unroll
        for (int msk = 1; msk < 32; msk <<= 1)
            v0 += __shfl_xor(v0, msk, 64);
        if (l31 == 0) {
            const int rl = (reg & 3) + 8 * (reg >> 2) + 4 * hi;
            sp[m0 + wm * 32 + rl] = v0;
        }
    }
}

// ---------- phase C: attend, 16-row halves. vb: ih = vb&1, b = (vb>>1)&7,
// ig = vb>>4. Window 47 rows in LDS; each window row loaded ONCE per wave
// and applied to the 4 output rows that use it (3.7x fewer LDS reads).
__device__ __forceinline__ void phase_attend(int vb, int tid,
                                             const float* __restrict__ X,
                                             const _Float16* __restrict__ Ah,
                                             const float* __restrict__ spart,
                                             float* __restrict__ out,
                                             char* lds)
{
    _Float16* W_lds = reinterpret_cast<_Float16*>(lds);   // 47*512 fp16 = 48128 B
    float*    p_lds = reinterpret_cast<float*>(lds + 48128); // 47 floats

    const int ih = vb & 1;
    const int b  = (vb >> 1) & 7;
    const int ig = vb >> 4;
    const int i0 = ig * 32 + ih * 16;

    if (ig == 0) { // outputs < 32: exact fp32 passthrough
        const float4* X4 = reinterpret_cast<const float4*>(X);
        float4* O4 = reinterpret_cast<float4*>(out);
        for (int idx = tid; idx < 16 * 128; idx += 256) {
            const int r = idx >> 7;
            const int c = idx & 127;
            const size_t off = (size_t)((i0 + r) * 8 + b) * 128 + c;
            O4[off] = X4[off];
        }
        return;
    }

    const int tau0 = i0 - 32;
    const int lane = tid & 63;
    const int wbase = __builtin_amdgcn_readfirstlane(tid & ~63);

    // stage 47 window rows -> W_lds (3008 x 16B chunks; 3008 % 64 == 0)
    {
        const _Float16* src = Ah + (size_t)(tau0 * 8 + b) * 512;
#pragma unroll
        for (int it = 0; it < 12; ++it) {
            const int cbase = it * 256 + wbase;
            if (cbase < 3008) {
                const int c  = cbase + lane;
                const int r  = c >> 6;
                const int ch = c & 63;
                gload16(src + (size_t)r * 4096 + ch * 8,
                        (char*)W_lds + (size_t)cbase * 16);
            }
        }
    }

    // softmax weights for lt in [0,47)
    const int bj = tid & 7;
#pragma unroll
    for (int half = 0; half < 2; ++half) {
        const int lt = (tid >> 3) + half * 32;
        if (lt < 47) {
            float s = 0.f;
#pragma unroll
            for (int g = 0; g < 8; ++g)
                s += spart[(size_t)g * M + (size_t)(tau0 + lt) * 8 + bj];
            float mx = s;
#pragma unroll
            for (int msk = 1; msk < 8; msk <<= 1)
                mx = fmaxf(mx, __shfl_xor(mx, msk, 64));
            const float e = __expf(s - mx);
            float sum = e;
#pragma unroll
            for (int msk = 1; msk < 8; msk <<= 1)
                sum += __shfl_xor(sum, msk, 64);
            if (bj == b) p_lds[lt] = e / sum;
        }
    }

    asm volatile("s_waitcnt vmcnt(0)" ::: "memory");
    __syncthreads();

    // wave rg owns output rows i0+u0+q, q=0..3 (u0 = rg*4); window rows
    // lt = u0+u, u in [0,35); row feeds output q iff k = u-q in [0,32).
    const int rg = tid >> 6;
    const int u0 = rg * 4;
    float acc[4][8];
#pragma unroll
    for (int q = 0; q < 4; ++q)
#pragma unroll
        for (int j = 0; j < 8; ++j) acc[q][j] = 0.f;

    auto apply = [&](int u, int qlo, int qhi) {
        const int lt = u0 + u;
        const float pw = p_lds[lt];
        const half8 h = *reinterpret_cast<const half8*>(
            W_lds + (size_t)lt * 512 + lane * 8);
        float hf[8];
#pragma unroll
        for (int j = 0; j < 8; ++j) hf[j] = (float)h[j];
        for (int q = qlo; q <= qhi; ++q)
#pragma unroll
            for (int j = 0; j < 8; ++j)
                acc[q][j] = fmaf(pw, hf[j], acc[q][j]);
    };

#pragma unroll
    for (int u = 0; u < 3; ++u)  apply(u, 0, u);        // head: q <= u
    for (int u = 3; u < 32; ++u) apply(u, 0, 3);        // body: all q
#pragma unroll
    for (int u = 32; u < 35; ++u) apply(u, u - 31, 3);  // tail: q >= u-31

#pragma unroll
    for (int q = 0; q < 4; ++q) {
        float4* O4 = reinterpret_cast<float4*>(
            out + (size_t)((i0 + u0 + q) * 8 + b) * 512 + lane * 8);
        O4[0] = float4{acc[q][0], acc[q][1], acc[q][2], acc[q][3]};
        O4[1] = float4{acc[q][4], acc[q][5], acc[q][6], acc[q][7]};
    }
}

// ---------- single cooperative kernel ----------
__global__ void __launch_bounds__(256, 2) fused_all(
    const float* __restrict__ X, const float* __restrict__ Wm,
    const float* __restrict__ proj, float* __restrict__ out,
    _Float16* __restrict__ Ah, _Float16* __restrict__ Bt,
    float* __restrict__ spart, unsigned* __restrict__ sync)
{
    __shared__ char lds[49152];
    const int bid = blockIdx.x, tid = threadIdx.x;
    const int nblk = gridDim.x;

    phase_prep(bid, tid, nblk, X, Wm, Ah, Bt, lds);
    gbar(sync, nblk);
    phase_gemm(bid, tid, Ah, Bt, proj, spart, lds);
    gbar(sync + 16, nblk);
    phase_attend(bid, tid, X, Ah, spart, out, lds);
}

// ---------- non-coop fallback: round-7 three-kernel path ----------
__global__ __launch_bounds__(256) void k_prep(const float* X, const float* Wm,
                                              _Float16* Ah, _Float16* Bt) {
    __shared__ char lds[16640];
    // X part: grid 2048 -> one chunk per thread via grid-stride formula
    phase_prep(blockIdx.x, threadIdx.x, gridDim.x, X, Wm, Ah, Bt, lds);
}
__global__ __launch_bounds__(256) void k_gemm(const _Float16* Ah, const _Float16* Bt,
                                              const float* proj, float* spart) {
    __shared__ char lds[49152];
    phase_gemm(blockIdx.x, threadIdx.x, Ah, Bt, proj, spart, lds);
}
__global__ __launch_bounds__(256) void k_attend(const float* X, const _Float16* Ah,
                                                const float* spart, float* out) {
    __shared__ char lds[49152];
    phase_attend(blockIdx.x, threadIdx.x, X, Ah, spart, out, lds);
}

extern "C" void kernel_launch(void* const* d_in, const int* in_sizes, int n_in,
                              void* d_out, int out_size, void* d_ws, size_t ws_size,
                              hipStream_t stream)
{
    const float* X    = (const float*)d_in[0];
    const float* Wm   = (const float*)d_in[1];
    const float* proj = (const float*)d_in[2];
    float* out = (float*)d_out;

    _Float16* Ah   = (_Float16*)d_ws;              // 8 MB
    _Float16* Bt   = Ah + (size_t)M * D;           // 0.5 MB
    float*    sprt = (float*)(Bt + (size_t)D * D); // 8*M floats
    unsigned* sync = (unsigned*)((char*)d_ws + (16u << 20)); // 2 counters

    hipError_t err = hipMemsetAsync(sync, 0, 256, stream);
    if (err == hipSuccess) {
        void* args[8] = {(void*)&X, (void*)&Wm, (void*)&proj, (void*)&out,
                         (void*)&Ah, (void*)&Bt, (void*)&sprt, (void*)&sync};
        err = hipLaunchCooperativeKernel((void*)fused_all, dim3(512), dim3(256),
                                         args, 0, stream);
    }
    if (err != hipSuccess) {
        (void)hipGetLastError(); // clear
        k_prep<<<2048, 256, 0, stream>>>(X, Wm, Ah, Bt);
        k_gemm<<<512, 256, 0, stream>>>(Ah, Bt, proj, sprt);
        k_attend<<<512, 256, 0, stream>>>(X, Ah, sprt, out);
    }
}

// Round 9
// 36.789 us; speedup vs baseline: 4.6079x; 4.6079x over previous
//
#include <hip/hip_runtime.h>
#include <cstdint>

namespace {
constexpr int T = 1024;
constexpr int B = 8;
constexpr int D = 512;
constexpr int W = 32;
constexpr int M = T * B; // 8192 rows (t*B+b)
}

using half8  = __attribute__((ext_vector_type(8))) _Float16;
using f32x16 = __attribute__((ext_vector_type(16))) float;

__device__ __forceinline__ void gload16(const void* g, void* l) {
    __builtin_amdgcn_global_load_lds(
        (const __attribute__((address_space(1))) void*)g,
        (__attribute__((address_space(3))) void*)l, 16, 0, 0);
}

__device__ __forceinline__ float fast_tanh(float x) {
    float e = __expf(2.f * x);
    return 1.f - 2.f / (e + 1.f);
}

// ---- prep: X fp32 -> Ah fp16 [M][D] (all blocks); W -> Bt^T (blocks 0..63) ----
__global__ __launch_bounds__(256) void prep_merged(
    const float* __restrict__ X, const float* __restrict__ Wm,
    _Float16* __restrict__ Ah, _Float16* __restrict__ Bt)
{
    __shared__ float tile[64][65];
    const int tid = threadIdx.x;
    const int bid = blockIdx.x;

    {
        const int c = bid * 256 + tid;
        const float4* X4 = reinterpret_cast<const float4*>(X);
        const float4 v0 = X4[(size_t)c * 2];
        const float4 v1 = X4[(size_t)c * 2 + 1];
        half8 h;
        h[0] = (_Float16)v0.x; h[1] = (_Float16)v0.y; h[2] = (_Float16)v0.z; h[3] = (_Float16)v0.w;
        h[4] = (_Float16)v1.x; h[5] = (_Float16)v1.y; h[6] = (_Float16)v1.z; h[7] = (_Float16)v1.w;
        *reinterpret_cast<half8*>(Ah + (size_t)c * 8) = h;
    }

    if (bid < 64) {
        const int bd = bid & 7;
        const int be = bid >> 3;
        const int r  = tid >> 2;
        const int c0 = (tid & 3) * 16;
        const float* src = Wm + (size_t)(be * 64 + r) * 512 + bd * 64 + c0;
#pragma unroll
        for (int j = 0; j < 16; j += 4) {
            const float4 v = *reinterpret_cast<const float4*>(src + j);
            tile[r][c0 + j]     = v.x;
            tile[r][c0 + j + 1] = v.y;
            tile[r][c0 + j + 2] = v.z;
            tile[r][c0 + j + 3] = v.w;
        }
        __syncthreads();
        const int dd = tid >> 2;
        const int e0 = (tid & 3) * 16;
        half8 h0, h1;
#pragma unroll
        for (int j = 0; j < 8; ++j)  h0[j] = (_Float16)tile[e0 + j][dd];
#pragma unroll
        for (int j = 0; j < 8; ++j)  h1[j] = (_Float16)tile[e0 + 8 + j][dd];
        _Float16* dst = Bt + (size_t)(bd * 64 + dd) * 512 + be * 64 + e0;
        *reinterpret_cast<half8*>(dst)     = h0;
        *reinterpret_cast<half8*>(dst + 8) = h1;
    }
}

// ---- GEMM + tanh + proj-dot -> spart[8][M] ----
// Counted-vmcnt pipeline (T4): stage(next) at loop top; s_waitcnt vmcnt(6)
// waits only the CURRENT tile's 6 chunks, leaving next tile's 6 loads in
// flight across the barrier. Removes the 8 full prefetch drains of rounds
// 2-8 (the exposed ~500cy latency per K-step). Tile 64x128, 512 blocks.
__global__ __launch_bounds__(256) void gemm_scores(
    const _Float16* __restrict__ Ah, const _Float16* __restrict__ Bt,
    const float* __restrict__ proj, float* __restrict__ spart)
{
    __shared__ char lds_buf[49152]; // [2 bufs][A 8K | B 16K]

    const int tid  = threadIdx.x;
    const int lane = tid & 63;
    const int wv   = tid >> 6;
    const int wm   = wv >> 1;
    const int wn   = wv & 1;
    const int hi   = lane >> 5;
    const int l31  = lane & 31;
    const int l7   = lane & 7;

    const int bid  = blockIdx.x;
    const int wgid = (bid & 7) * 64 + (bid >> 3); // XCD-aware swizzle
    const int mb   = wgid >> 2;
    const int nb   = wgid & 3;
    const int m0   = mb * 64;
    const int n0   = nb * 128;

    const int wbase = __builtin_amdgcn_readfirstlane(tid & ~63);

    f32x16 acc0 = {}, acc1 = {};

    auto stage = [&](int bufi, int kt) {
        char* abase = lds_buf + bufi * 24576;
        char* bbase = abase + 8192;
        const int kbase = kt * 64;
#pragma unroll
        for (int i = 0; i < 2; ++i) {
            const int c   = i * 256 + tid;
            const int row = c >> 3;
            const int ch  = c & 7;
            const int koff = kbase + ((ch ^ (row & 7)) << 3);
            gload16(Ah + (size_t)(m0 + row) * 512 + koff,
                    abase + (size_t)(i * 256 + wbase) * 16);
        }
#pragma unroll
        for (int i = 0; i < 4; ++i) {
            const int c   = i * 256 + tid;
            const int row = c >> 3;
            const int ch  = c & 7;
            const int koff = kbase + ((ch ^ (row & 7)) << 3);
            gload16(Bt + (size_t)(n0 + row) * 512 + koff,
                    bbase + (size_t)(i * 256 + wbase) * 16);
        }
    };

    stage(0, 0); // 6 loads in flight; NO drain here (counted wait in-loop)

    int cur = 0;
    const int rowA  = wm * 32 + l31;
    const int colB0 = wn * 64 + l31;
    const int colB1 = colB0 + 32;

    for (int kt = 0; kt < 8; ++kt) {
        if (kt < 7) {
            stage(cur ^ 1, kt + 1);                    // +6 newer loads
            asm volatile("s_waitcnt vmcnt(6)" ::: "memory"); // cur's 6 landed
        } else {
            asm volatile("s_waitcnt vmcnt(0)" ::: "memory"); // last tile
        }
        __syncthreads(); // all threads' DMA for buf[cur] complete

        const char* Ab = lds_buf + cur * 24576;
        const char* Bb = Ab + 8192;

        half8 af[4], bf0[4], bf1[4];
#pragma unroll
        for (int s = 0; s < 4; ++s) {
            const int ch = ((2 * s + hi) ^ l7) << 4;
            af[s]  = *reinterpret_cast<const half8*>(Ab + rowA  * 128 + ch);
            bf0[s] = *reinterpret_cast<const half8*>(Bb + colB0 * 128 + ch);
            bf1[s] = *reinterpret_cast<const half8*>(Bb + colB1 * 128 + ch);
        }
        __builtin_amdgcn_s_setprio(1);
#pragma unroll
        for (int s = 0; s < 4; ++s) {
            acc0 = __builtin_amdgcn_mfma_f32_32x32x16_f16(af[s], bf0[s], acc0, 0, 0, 0);
            acc1 = __builtin_amdgcn_mfma_f32_32x32x16_f16(af[s], bf1[s], acc1, 0, 0, 0);
        }
        __builtin_amdgcn_s_setprio(0);

        __syncthreads(); // all reads of buf[cur] done before kt+1 overwrites it
        cur ^= 1;
    }

    const float pj0 = proj[n0 + wn * 64 + l31];
    const float pj1 = proj[n0 + wn * 64 + 32 + l31];
    float* sp = spart + (size_t)(nb * 2 + wn) * M;

#pragma unroll
    for (int reg = 0; reg < 16; ++reg) {
        float v0 = fast_tanh(acc0[reg]) * pj0 + fast_tanh(acc1[reg]) * pj1;
#pragma unroll
        for (int msk = 1; msk < 32; msk <<= 1)
            v0 += __shfl_xor(v0, msk, 64);
        if (l31 == 0) {
            const int rl = (reg & 3) + 8 * (reg >> 2) + 4 * hi;
            sp[m0 + wm * 32 + rl] = v0;
        }
    }
}

// ---- attend: 16-row halves (proven correct in round 8's fused run).
// vb: ih = vb&1, b = (vb>>1)&7, ig = vb>>4. 47-row window in 48 KB LDS
// -> 2 blocks/CU (vs 1 at 64 KB). Each window row read once per wave and
// applied to the <=4 output rows that use it.
__global__ __launch_bounds__(256) void attend_kernel(
    const float* __restrict__ X, const _Float16* __restrict__ Ah,
    const float* __restrict__ spart, float* __restrict__ out)
{
    __shared__ char lds[49152];
    _Float16* W_lds = reinterpret_cast<_Float16*>(lds);      // 47*512 fp16
    float*    p_lds = reinterpret_cast<float*>(lds + 48128); // 47 floats

    const int vb  = blockIdx.x;
    const int tid = threadIdx.x;
    const int ih  = vb & 1;
    const int b   = (vb >> 1) & 7;
    const int ig  = vb >> 4;
    const int i0  = ig * 32 + ih * 16;

    if (ig == 0) { // outputs < 32: exact fp32 passthrough
        const float4* X4 = reinterpret_cast<const float4*>(X);
        float4* O4 = reinterpret_cast<float4*>(out);
        for (int idx = tid; idx < 16 * 128; idx += 256) {
            const int r = idx >> 7;
            const int c = idx & 127;
            const size_t off = (size_t)((i0 + r) * 8 + b) * 128 + c;
            O4[off] = X4[off];
        }
        return;
    }

    const int tau0 = i0 - 32;
    const int lane = tid & 63;
    const int wbase = __builtin_amdgcn_readfirstlane(tid & ~63);

    // stage 47 window rows -> W_lds (3008 x 16B chunks; 3008 % 64 == 0)
    {
        const _Float16* src = Ah + (size_t)(tau0 * 8 + b) * 512;
#pragma unroll
        for (int it = 0; it < 12; ++it) {
            const int cbase = it * 256 + wbase;   // wave-uniform chunk base
            if (cbase < 3008) {
                const int c  = cbase + lane;
                const int r  = c >> 6;
                const int ch = c & 63;
                gload16(src + (size_t)r * 4096 + ch * 8,
                        (char*)W_lds + (size_t)cbase * 16);
            }
        }
    }

    // softmax weights for lt in [0,47)
    const int bj = tid & 7;
#pragma unroll
    for (int half = 0; half < 2; ++half) {
        const int lt = (tid >> 3) + half * 32;
        if (lt < 47) {
            float s = 0.f;
#pragma unroll
            for (int g = 0; g < 8; ++g)
                s += spart[(size_t)g * M + (size_t)(tau0 + lt) * 8 + bj];
            float mx = s;
#pragma unroll
            for (int msk = 1; msk < 8; msk <<= 1)
                mx = fmaxf(mx, __shfl_xor(mx, msk, 64));
            const float e = __expf(s - mx);
            float sum = e;
#pragma unroll
            for (int msk = 1; msk < 8; msk <<= 1)
                sum += __shfl_xor(sum, msk, 64);
            if (bj == b) p_lds[lt] = e / sum;
        }
    }

    asm volatile("s_waitcnt vmcnt(0)" ::: "memory");
    __syncthreads();

    // wave rg owns output rows i0+u0+q, q=0..3 (u0 = rg*4); window rows
    // lt = u0+u, u in [0,35); row feeds output q iff k = u-q in [0,32).
    const int rg = tid >> 6;
    const int u0 = rg * 4;
    float acc[4][8];
#pragma unroll
    for (int q = 0; q < 4; ++q)
#pragma unroll
        for (int j = 0; j < 8; ++j) acc[q][j] = 0.f;

    auto apply = [&](int u, int qlo, int qhi) {
        const int lt = u0 + u;
        const float pw = p_lds[lt];
        const half8 h = *reinterpret_cast<const half8*>(
            W_lds + (size_t)lt * 512 + lane * 8);
        float hf[8];
#pragma unroll
        for (int j = 0; j < 8; ++j) hf[j] = (float)h[j];
        for (int q = qlo; q <= qhi; ++q)
#pragma unroll
            for (int j = 0; j < 8; ++j)
                acc[q][j] = fmaf(pw, hf[j], acc[q][j]);
    };

#pragma unroll
    for (int u = 0; u < 3; ++u)  apply(u, 0, u);        // head: q <= u
    for (int u = 3; u < 32; ++u) apply(u, 0, 3);        // body: all q
#pragma unroll
    for (int u = 32; u < 35; ++u) apply(u, u - 31, 3);  // tail: q >= u-31

#pragma unroll
    for (int q = 0; q < 4; ++q) {
        float4* O4 = reinterpret_cast<float4*>(
            out + (size_t)((i0 + u0 + q) * 8 + b) * 512 + lane * 8);
        O4[0] = float4{acc[q][0], acc[q][1], acc[q][2], acc[q][3]};
        O4[1] = float4{acc[q][4], acc[q][5], acc[q][6], acc[q][7]};
    }
}

extern "C" void kernel_launch(void* const* d_in, const int* in_sizes, int n_in,
                              void* d_out, int out_size, void* d_ws, size_t ws_size,
                              hipStream_t stream)
{
    const float* X    = (const float*)d_in[0];
    const float* Wm   = (const float*)d_in[1];
    const float* proj = (const float*)d_in[2];
    float* out = (float*)d_out;

    _Float16* Ah   = (_Float16*)d_ws;              // 8 MB
    _Float16* Bt   = Ah + (size_t)M * D;           // 0.5 MB
    float*    sprt = (float*)(Bt + (size_t)D * D); // 8*M floats

    prep_merged<<<2048, 256, 0, stream>>>(X, Wm, Ah, Bt);
    gemm_scores<<<512, 256, 0, stream>>>(Ah, Bt, proj, sprt);
    attend_kernel<<<(T / W) * B * 2, 256, 0, stream>>>(X, Ah, sprt, out);
}